// Round 8
// baseline (724.149 us; speedup 1.0000x reference)
//
#include <hip/hip_runtime.h>
#include <hip/hip_bf16.h>

#define D_MODEL 1024
#define D_INNER 2048
#define D_STATE 16
#define DT_RANK 64
#define BATCH 2
#define SEQLEN 4096
#define BL (BATCH * SEQLEN)           // 8192 rows (b,l)
#define NPROJ (DT_RANK + 2 * D_STATE) // 96
#define CH 64                         // scan chunk length
#define NCH (SEQLEN / CH)             // 64 chunks

typedef __attribute__((ext_vector_type(8))) short bf16x8;
typedef __attribute__((ext_vector_type(4))) float f32x4;
struct S4 { short x, y, z, w; };

__device__ __forceinline__ float sigmoidf_(float v) {
    return 1.0f / (1.0f + __expf(-v));
}

__device__ __forceinline__ unsigned short bf16_rne(float f) {
    unsigned u = __float_as_uint(f);
    unsigned r = u + 0x7FFFu + ((u >> 16) & 1u);
    return (unsigned short)(r >> 16);
}

__device__ __forceinline__ float bf2f(short s) {
    return __uint_as_float(((unsigned)(unsigned short)s) << 16);
}

#define GLOAD(gptr, dptr)                                              \
    __builtin_amdgcn_global_load_lds(                                  \
        (const __attribute__((address_space(1))) void*)(gptr),         \
        (__attribute__((address_space(3))) void*)(dptr), 16, 0, 0)

// ---------------------------------------------------------------------------
// Split fp32 -> bf16 hi + bf16 lo (lo = rne(x - hi)); rel err ~2^-17.
// ---------------------------------------------------------------------------
__global__ __launch_bounds__(256)
void cvt_split(const float* __restrict__ in, short* __restrict__ hi,
               short* __restrict__ lo, int n4) {
    const int i = blockIdx.x * 256 + threadIdx.x;
    if (i >= n4) return;
    const float4 v = reinterpret_cast<const float4*>(in)[i];
    const float f[4] = {v.x, v.y, v.z, v.w};
    S4 h, l;
    short hb[4], lb[4];
#pragma unroll
    for (int j = 0; j < 4; ++j) {
        const unsigned short hh = bf16_rne(f[j]);
        const float hf = __uint_as_float((unsigned)hh << 16);
        hb[j] = (short)hh;
        lb[j] = (short)bf16_rne(f[j] - hf);
    }
    h.x = hb[0]; h.y = hb[1]; h.z = hb[2]; h.w = hb[3];
    l.x = lb[0]; l.y = lb[1]; l.z = lb[2]; l.w = lb[3];
    *reinterpret_cast<S4*>(hi + (size_t)i * 4) = h;
    *reinterpret_cast<S4*>(lo + (size_t)i * 4) = l;
}

// ---------------------------------------------------------------------------
// 256x128-tile bf16x3 MFMA NT GEMM, 8 waves (512 thr), BK=32, dbuf LDS (96 KB
// dynamic), counted vmcnt(6). Per K-step compute = 384 MFMA (~1860 CU-cyc)
// fully covers HBM latency of the next tile's stage. T1 XCD swizzle; T2 XOR
// swizzle via pre-swizzled global source.
// EPI 0: C0[row*ldc + n]. EPI 2: parity split - even n -> C0[row*ldc + n/2],
// odd n -> C1[row*ldc + n/2]  (merged x/z GEMM over interleaved W_in rows).
// Requires M%256==0, N%128==0, K%32==0, K>=64, grid%8==0.
// ---------------------------------------------------------------------------
template <int EPI>
__global__ __launch_bounds__(512)
void gemm_bt256(const short* __restrict__ Ahi, const short* __restrict__ Alo,
                const short* __restrict__ Bhi, const short* __restrict__ Blo,
                float* __restrict__ C0, float* __restrict__ C1,
                int K, int lda, int ldb, int ldc) {
    extern __shared__ short smem[];
    short* sA = smem;            // [buf][h][256][32]: buf stride 16384, h 8192
    short* sB = smem + 32768;    // [buf][h][128][32]: buf stride 8192,  h 4096
    const int t = threadIdx.x;
    const int w = t >> 6, l = t & 63;

    // T1: XCD swizzle (callers guarantee nwg % 8 == 0)
    const int nwg = gridDim.x * gridDim.y;
    int bid = blockIdx.y * gridDim.x + blockIdx.x;
    bid = (bid & 7) * (nwg >> 3) + (bid >> 3);
    const int m0 = (bid / gridDim.x) * 256, n0 = (bid % gridDim.x) * 128;
    const int wr = w >> 1, wc = w & 1;     // wave quadrant: 4 x 2

    const int r4 = l >> 2;                               // row within 16-seg
    const int kc_src = ((l & 3) ^ ((l >> 3) & 3)) << 3;  // T2 source chunk
    const int frow = l & 15;
    const int kb = (((l >> 4) ^ ((frow >> 1) & 3)) << 3);  // T2 read chunk

    f32x4 acc[4][4] = {};

    // 6 global_load_lds per wave per K-step: A-hi x2, A-lo x2, B-hi, B-lo.
    auto STAGE = [&](int buf, int k0) {
        const int sa0 = w, sa1 = 8 + w;
        GLOAD(Ahi + (size_t)(m0 + sa0 * 16 + r4) * lda + k0 + kc_src,
              sA + buf * 16384 + sa0 * 512);
        GLOAD(Ahi + (size_t)(m0 + sa1 * 16 + r4) * lda + k0 + kc_src,
              sA + buf * 16384 + sa1 * 512);
        GLOAD(Alo + (size_t)(m0 + sa0 * 16 + r4) * lda + k0 + kc_src,
              sA + buf * 16384 + 8192 + sa0 * 512);
        GLOAD(Alo + (size_t)(m0 + sa1 * 16 + r4) * lda + k0 + kc_src,
              sA + buf * 16384 + 8192 + sa1 * 512);
        GLOAD(Bhi + (size_t)(n0 + w * 16 + r4) * ldb + k0 + kc_src,
              sB + buf * 8192 + w * 512);
        GLOAD(Blo + (size_t)(n0 + w * 16 + r4) * ldb + k0 + kc_src,
              sB + buf * 8192 + 4096 + w * 512);
    };

    auto COMPUTE = [&](int buf) {
        bf16x8 a[2][4], b[2][4];
        const short* pA = sA + buf * 16384;
        const short* pB = sB + buf * 8192;
#pragma unroll
        for (int f = 0; f < 4; ++f) {
            a[0][f] = *reinterpret_cast<const bf16x8*>(&pA[(wr * 64 + f * 16 + frow) * 32 + kb]);
            a[1][f] = *reinterpret_cast<const bf16x8*>(&pA[8192 + (wr * 64 + f * 16 + frow) * 32 + kb]);
            b[0][f] = *reinterpret_cast<const bf16x8*>(&pB[(wc * 64 + f * 16 + frow) * 32 + kb]);
            b[1][f] = *reinterpret_cast<const bf16x8*>(&pB[4096 + (wc * 64 + f * 16 + frow) * 32 + kb]);
        }
#pragma unroll
        for (int fi = 0; fi < 4; ++fi)
#pragma unroll
            for (int fj = 0; fj < 4; ++fj) {
                acc[fi][fj] = __builtin_amdgcn_mfma_f32_16x16x32_bf16(
                    a[0][fi], b[0][fj], acc[fi][fj], 0, 0, 0);
                acc[fi][fj] = __builtin_amdgcn_mfma_f32_16x16x32_bf16(
                    a[1][fi], b[0][fj], acc[fi][fj], 0, 0, 0);
                acc[fi][fj] = __builtin_amdgcn_mfma_f32_16x16x32_bf16(
                    a[0][fi], b[1][fj], acc[fi][fj], 0, 0, 0);
            }
    };

    const int NT = K >> 5;
    STAGE(0, 0);
    for (int tt = 0; tt < NT - 1; ++tt) {
        const int cur = tt & 1;
        STAGE(cur ^ 1, (tt + 1) << 5);
        __builtin_amdgcn_sched_barrier(0);
        asm volatile("s_waitcnt vmcnt(6)" ::: "memory");  // tile tt's 6 loads done
        __builtin_amdgcn_s_barrier();                     // A: tile tt visible
        COMPUTE(cur);
        __builtin_amdgcn_sched_barrier(0);
        __builtin_amdgcn_s_barrier();                     // B: buf[cur] reusable
    }
    {
        const int cur = (NT - 1) & 1;
        __builtin_amdgcn_sched_barrier(0);
        asm volatile("s_waitcnt vmcnt(0)" ::: "memory");
        __builtin_amdgcn_s_barrier();
        COMPUTE(cur);
    }

    // C/D layout (m89-verified): col = lane&15, row = (lane>>4)*4 + reg
    const int crow = (l >> 4) << 2;
    const int ccol = l & 15;
#pragma unroll
    for (int fi = 0; fi < 4; ++fi)
#pragma unroll
        for (int fj = 0; fj < 4; ++fj) {
            const int n = n0 + wc * 64 + fj * 16 + ccol;
#pragma unroll
            for (int r = 0; r < 4; ++r) {
                const float v = acc[fi][fj][r];
                const size_t row = (size_t)(m0 + wr * 64 + fi * 16 + crow + r);
                if (EPI == 2) {
                    float* dst = (n & 1) ? C1 : C0;
                    dst[row * ldc + (n >> 1)] = v;
                } else {
                    C0[row * ldc + n] = v;
                }
            }
        }
}

// ---------------------------------------------------------------------------
// 128x128 bf16x3 MFMA NT GEMM (round-7 verified) - used for the delta GEMM.
// dbuf + counted vmcnt(8). EPI 1 = softplus(v + bias[n]).
// ---------------------------------------------------------------------------
template <int EPI>
__global__ __launch_bounds__(256)
void gemm_bf16x3(const short* __restrict__ Ahi, const short* __restrict__ Alo,
                 const short* __restrict__ Bhi, const short* __restrict__ Blo,
                 float* __restrict__ C, int K, int lda, int ldb, int ldc,
                 const float* __restrict__ bias) {
    __shared__ short sA[2][2][128][32];
    __shared__ short sB[2][2][128][32];
    const int t = threadIdx.x;
    const int w = t >> 6, l = t & 63;

    const int nwg = gridDim.x * gridDim.y;
    int bid = blockIdx.y * gridDim.x + blockIdx.x;
    if ((nwg & 7) == 0) bid = (bid & 7) * (nwg >> 3) + (bid >> 3);
    const int m0 = (bid / gridDim.x) * 128, n0 = (bid % gridDim.x) * 128;
    const int wr = w >> 1, wc = w & 1;

    const short* gsrc;
    short* sd0;
    short* sd1;
    int ld, tile0;
    if (w == 0)      { gsrc = Ahi; sd0 = &sA[0][0][0][0]; sd1 = &sA[1][0][0][0]; tile0 = m0; ld = lda; }
    else if (w == 1) { gsrc = Alo; sd0 = &sA[0][1][0][0]; sd1 = &sA[1][1][0][0]; tile0 = m0; ld = lda; }
    else if (w == 2) { gsrc = Bhi; sd0 = &sB[0][0][0][0]; sd1 = &sB[1][0][0][0]; tile0 = n0; ld = ldb; }
    else             { gsrc = Blo; sd0 = &sB[0][1][0][0]; sd1 = &sB[1][1][0][0]; tile0 = n0; ld = ldb; }
    const int kc_src = ((l & 3) ^ ((l >> 3) & 3)) << 3;
    const size_t grow = (size_t)(tile0 + (l >> 2)) * ld + kc_src;

    f32x4 acc[4][4] = {};
    const int frow = l & 15;
    const int kb = (((l >> 4) ^ ((frow >> 1) & 3)) << 3);

    auto STAGE = [&](short* sdst, int k0) {
#pragma unroll
        for (int i = 0; i < 8; ++i) {
            const short* g = gsrc + grow + (size_t)(i << 4) * ld + k0;
            GLOAD(g, sdst + (i << 9));
        }
    };

    auto COMPUTE = [&](int cur) {
        bf16x8 a[2][4], b[2][4];
#pragma unroll
        for (int f = 0; f < 4; ++f) {
            a[0][f] = *reinterpret_cast<const bf16x8*>(&sA[cur][0][wr * 64 + f * 16 + frow][kb]);
            a[1][f] = *reinterpret_cast<const bf16x8*>(&sA[cur][1][wr * 64 + f * 16 + frow][kb]);
            b[0][f] = *reinterpret_cast<const bf16x8*>(&sB[cur][0][wc * 64 + f * 16 + frow][kb]);
            b[1][f] = *reinterpret_cast<const bf16x8*>(&sB[cur][1][wc * 64 + f * 16 + frow][kb]);
        }
#pragma unroll
        for (int fi = 0; fi < 4; ++fi)
#pragma unroll
            for (int fj = 0; fj < 4; ++fj) {
                acc[fi][fj] = __builtin_amdgcn_mfma_f32_16x16x32_bf16(
                    a[0][fi], b[0][fj], acc[fi][fj], 0, 0, 0);
                acc[fi][fj] = __builtin_amdgcn_mfma_f32_16x16x32_bf16(
                    a[1][fi], b[0][fj], acc[fi][fj], 0, 0, 0);
                acc[fi][fj] = __builtin_amdgcn_mfma_f32_16x16x32_bf16(
                    a[0][fi], b[1][fj], acc[fi][fj], 0, 0, 0);
            }
    };

    const int NT = K >> 5;
    STAGE(sd0, 0);
    for (int tt = 0; tt < NT - 1; ++tt) {
        const int cur = tt & 1;
        STAGE(cur ? sd0 : sd1, (tt + 1) << 5);
        __builtin_amdgcn_sched_barrier(0);
        asm volatile("s_waitcnt vmcnt(8)" ::: "memory");
        __builtin_amdgcn_s_barrier();
        COMPUTE(cur);
        __builtin_amdgcn_sched_barrier(0);
        __builtin_amdgcn_s_barrier();
    }
    {
        const int cur = (NT - 1) & 1;
        __builtin_amdgcn_sched_barrier(0);
        asm volatile("s_waitcnt vmcnt(0)" ::: "memory");
        __builtin_amdgcn_s_barrier();
        COMPUTE(cur);
    }

    const int crow = (l >> 4) << 2;
    const int ccol = l & 15;
#pragma unroll
    for (int fi = 0; fi < 4; ++fi)
#pragma unroll
        for (int fj = 0; fj < 4; ++fj) {
            const int n = n0 + wc * 64 + fj * 16 + ccol;
#pragma unroll
            for (int r = 0; r < 4; ++r) {
                float v = acc[fi][fj][r];
                if (EPI == 1) {
                    v += bias[n];
                    v = fmaxf(v, 0.f) + log1pf(__expf(-fabsf(v)));  // stable softplus
                }
                C[(size_t)(m0 + wr * 64 + fi * 16 + crow + r) * ldc + n] = v;
            }
        }
}

// ---------------------------------------------------------------------------
// Tall-skinny bf16x3 MFMA GEMM for x_proj + dt hi/lo emit.
// ---------------------------------------------------------------------------
__global__ __launch_bounds__(256)
void gemm96(const short* __restrict__ Xhi, const short* __restrict__ Xlo,
            const short* __restrict__ Whi, const short* __restrict__ Wlo,
            float* __restrict__ C, short* __restrict__ dthi,
            short* __restrict__ dtlo) {
    const int t = threadIdx.x;
    const int w = t >> 6, l = t & 63;
    const int m0 = blockIdx.x * 32;
    const int rfrag = (w >> 1) * 16;
    const int cbase = (w & 1) * 48;
    const int lrow = l & 15;
    const int koff0 = (l >> 4) << 3;
    f32x4 acc[3] = {};
    const size_t arow = (size_t)(m0 + rfrag + lrow) * D_INNER;
#pragma unroll 2
    for (int k0 = 0; k0 < D_INNER; k0 += 32) {
        const int ko = k0 + koff0;
        const bf16x8 ah = *reinterpret_cast<const bf16x8*>(Xhi + arow + ko);
        const bf16x8 al = *reinterpret_cast<const bf16x8*>(Xlo + arow + ko);
#pragma unroll
        for (int jj = 0; jj < 3; ++jj) {
            const size_t brow = (size_t)(cbase + jj * 16 + lrow) * D_INNER + ko;
            const bf16x8 bh = *reinterpret_cast<const bf16x8*>(Whi + brow);
            const bf16x8 bl = *reinterpret_cast<const bf16x8*>(Wlo + brow);
            acc[jj] = __builtin_amdgcn_mfma_f32_16x16x32_bf16(ah, bh, acc[jj], 0, 0, 0);
            acc[jj] = __builtin_amdgcn_mfma_f32_16x16x32_bf16(al, bh, acc[jj], 0, 0, 0);
            acc[jj] = __builtin_amdgcn_mfma_f32_16x16x32_bf16(ah, bl, acc[jj], 0, 0, 0);
        }
    }
    const int crow = (l >> 4) << 2;
#pragma unroll
    for (int jj = 0; jj < 3; ++jj) {
        const int col = cbase + jj * 16 + lrow;
#pragma unroll
        for (int r = 0; r < 4; ++r) {
            const int m = m0 + rfrag + crow + r;
            const float v = acc[jj][r];
            C[(size_t)m * NPROJ + col] = v;
            if (col < DT_RANK) {
                const unsigned short hh = bf16_rne(v);
                dthi[(size_t)m * DT_RANK + col] = (short)hh;
                dtlo[(size_t)m * DT_RANK + col] =
                    (short)bf16_rne(v - __uint_as_float((unsigned)hh << 16));
            }
        }
    }
}

// ---------------------------------------------------------------------------
// Depthwise causal conv (D_CONV=4) + bias + SiLU -> bf16 hi/lo split output.
// ---------------------------------------------------------------------------
__global__ __launch_bounds__(256)
void conv_silu_k(const float* __restrict__ xr, const float* __restrict__ cw,
                 const float* __restrict__ cb, short* __restrict__ xchi,
                 short* __restrict__ xclo) {
    const int idx = blockIdx.x * 256 + threadIdx.x;
    const int d = idx & (D_INNER - 1);
    const int bl = idx >> 11;
    const int l = bl & (SEQLEN - 1);
    const float4 w4 = *reinterpret_cast<const float4*>(cw + (size_t)d * 4);
    const float wj[4] = {w4.x, w4.y, w4.z, w4.w};
    float acc = cb[d];
#pragma unroll
    for (int j = 0; j < 4; ++j) {
        const int ll = l - 3 + j;
        if (ll >= 0)
            acc += xr[(size_t)(bl - 3 + j) * D_INNER + d] * wj[j];
    }
    const float v = acc * sigmoidf_(acc);
    const unsigned short hh = bf16_rne(v);
    xchi[idx] = (short)hh;
    xclo[idx] = (short)bf16_rne(v - __uint_as_float((unsigned)hh << 16));
}

// ---------------------------------------------------------------------------
// Selective scan, chunked 3-pass. x reconstructed from bf16 hi/lo (err 2^-17).
// ---------------------------------------------------------------------------
__global__ __launch_bounds__(256)
void scan1(const float* __restrict__ delta, const short* __restrict__ xchi,
           const short* __restrict__ xclo, const float* __restrict__ dtbc,
           const float* __restrict__ A_log, float* __restrict__ sum_delta,
           float* __restrict__ S_end) {
    const int d = blockIdx.x * 256 + threadIdx.x;
    const int b = blockIdx.y;
    const int c = blockIdx.z;
    __shared__ float bc[CH][32];
    for (int i = threadIdx.x; i < CH * 32; i += 256) {
        const int row = i >> 5, col = i & 31;
        bc[row][col] = dtbc[(size_t)(b * SEQLEN + c * CH + row) * NPROJ + DT_RANK + col];
    }
    __syncthreads();
    float A[16];
#pragma unroll
    for (int n = 0; n < 16; ++n) A[n] = -__expf(A_log[(size_t)d * 16 + n]);
    float s[16] = {0.f};
    float sd = 0.f;
    const size_t base = ((size_t)b * SEQLEN + (size_t)c * CH) * D_INNER + d;
    for (int li = 0; li < CH; ++li) {
        const size_t o = base + (size_t)li * D_INNER;
        const float dl = delta[o];
        const float xv = bf2f(xchi[o]) + bf2f(xclo[o]);
        sd += dl;
        const float dx = dl * xv;
#pragma unroll
        for (int n = 0; n < 16; ++n) {
            const float a = __expf(dl * A[n]);
            s[n] = fmaf(s[n], a, dx * bc[li][n]);
        }
    }
    sum_delta[((size_t)c * BATCH + b) * D_INNER + d] = sd;
#pragma unroll
    for (int n = 0; n < 16; ++n)
        S_end[(((size_t)c * BATCH + b) * 16 + n) * D_INNER + d] = s[n];
}

// Thread per (b,d,n); in-place: S holds end-states on entry, init-states on exit.
__global__ __launch_bounds__(256)
void scan2(const float* __restrict__ sum_delta, float* __restrict__ S,
           const float* __restrict__ A_log) {
    const int idx = blockIdx.x * 256 + threadIdx.x;   // [0, BATCH*16*D_INNER)
    const int d = idx & (D_INNER - 1);
    const int n = (idx >> 11) & 15;
    const int b = idx >> 15;
    const float A = -__expf(A_log[(size_t)d * 16 + n]);
    float carry = 0.f;
    for (int c = 0; c < NCH; ++c) {
        const float sd = sum_delta[((size_t)c * BATCH + b) * D_INNER + d];
        const size_t o = (((size_t)c * BATCH + b) * 16 + n) * D_INNER + d;
        const float se = S[o];
        S[o] = carry;
        carry = fmaf(carry, __expf(sd * A), se);
    }
}

// scan3: writes gated y as bf16 hi/lo IN-PLACE over xchi/xclo.
__global__ __launch_bounds__(256)
void scan3(const float* __restrict__ delta, short* __restrict__ xchi,
           short* __restrict__ xclo, const float* __restrict__ z,
           const float* __restrict__ dtbc, const float* __restrict__ A_log,
           const float* __restrict__ S_init, const float* __restrict__ Dp) {
    const int d = blockIdx.x * 256 + threadIdx.x;
    const int b = blockIdx.y;
    const int c = blockIdx.z;
    __shared__ float bc[CH][32];
    for (int i = threadIdx.x; i < CH * 32; i += 256) {
        const int row = i >> 5, col = i & 31;
        bc[row][col] = dtbc[(size_t)(b * SEQLEN + c * CH + row) * NPROJ + DT_RANK + col];
    }
    __syncthreads();
    float A[16];
#pragma unroll
    for (int n = 0; n < 16; ++n) A[n] = -__expf(A_log[(size_t)d * 16 + n]);
    float s[16];
#pragma unroll
    for (int n = 0; n < 16; ++n)
        s[n] = S_init[(((size_t)c * BATCH + b) * 16 + n) * D_INNER + d];
    const float Dv = Dp[d];
    const size_t base = ((size_t)b * SEQLEN + (size_t)c * CH) * D_INNER + d;
    for (int li = 0; li < CH; ++li) {
        const size_t o = base + (size_t)li * D_INNER;
        const float dl = delta[o];
        const float xv = bf2f(xchi[o]) + bf2f(xclo[o]);
        const float dx = dl * xv;
        float y = 0.f;
#pragma unroll
        for (int n = 0; n < 16; ++n) {
            const float a = __expf(dl * A[n]);
            s[n] = fmaf(s[n], a, dx * bc[li][n]);
            y = fmaf(s[n], bc[li][16 + n], y);
        }
        const float zv = z[o];
        const float yv = (y + Dv * xv) * (zv * sigmoidf_(zv));
        const unsigned short hh = bf16_rne(yv);
        xchi[o] = (short)hh;
        xclo[o] = (short)bf16_rne(yv - __uint_as_float((unsigned)hh << 16));
    }
}

// ---------------------------------------------------------------------------
extern "C" void kernel_launch(void* const* d_in, const int* in_sizes, int n_in,
                              void* d_out, int out_size, void* d_ws, size_t ws_size,
                              hipStream_t stream) {
    const float* hidden   = (const float*)d_in[0];
    const float* W_in     = (const float*)d_in[1];
    const float* conv_w   = (const float*)d_in[2];
    const float* conv_b   = (const float*)d_in[3];
    const float* x_proj_w = (const float*)d_in[4];
    const float* dt_w     = (const float*)d_in[5];
    const float* dt_b     = (const float*)d_in[6];
    const float* A_log    = (const float*)d_in[7];
    const float* Dp       = (const float*)d_in[8];
    const float* W_out    = (const float*)d_in[9];
    float* out = (float*)d_out;

    // Workspace (floats), peak ~226 MB:
    float* ws    = (float*)d_ws;
    float* xbuf  = ws;                                    // BL*D_INNER (x; delta)
    float* zbuf  = xbuf + (size_t)BL * D_INNER;           // BL*D_INNER (z; later W_out hi/lo)
    float* xcreg = zbuf + (size_t)BL * D_INNER;           // BL*D_INNER (splits; xc hi/lo; y hi/lo)
    float* dtbc  = xcreg + (size_t)BL * D_INNER;          // BL*NPROJ
    float* sumd  = dtbc + (size_t)BL * NPROJ;             // NCH*BATCH*D_INNER
    float* Send  = sumd + (size_t)NCH * BATCH * D_INNER;  // NCH*BATCH*16*D_INNER

    short* xpwhi = (short*)(Send + (size_t)NCH * BATCH * 16 * D_INNER);
    short* xpwlo = xpwhi + (size_t)NPROJ * D_INNER;
    short* dtwhi = xpwlo + (size_t)NPROJ * D_INNER;
    short* dtwlo = dtwhi + (size_t)D_INNER * DT_RANK;
    short* dthi  = dtwlo + (size_t)D_INNER * DT_RANK;
    short* dtlo  = dthi + (size_t)BL * DT_RANK;

    short* hxhi  = (short*)xcreg;                          // BL*D_MODEL
    short* hxlo  = hxhi + (size_t)BL * D_MODEL;
    short* winhi = hxlo + (size_t)BL * D_MODEL;            // 2*D_INNER*D_MODEL
    short* winlo = winhi + (size_t)2 * D_INNER * D_MODEL;

    const dim3 thr(256);

    // 0) split-convert hidden, W_in, x_proj_w, dt_w to bf16 hi/lo
    cvt_split<<<dim3(BL * D_MODEL / 1024), thr, 0, stream>>>(hidden, hxhi, hxlo, BL * D_MODEL / 4);
    cvt_split<<<dim3(2 * D_INNER * D_MODEL / 1024), thr, 0, stream>>>(W_in, winhi, winlo, 2 * D_INNER * D_MODEL / 4);
    cvt_split<<<dim3(NPROJ * D_INNER / 1024), thr, 0, stream>>>(x_proj_w, xpwhi, xpwlo, NPROJ * D_INNER / 4);
    cvt_split<<<dim3(D_INNER * DT_RANK / 1024), thr, 0, stream>>>(dt_w, dtwhi, dtwlo, D_INNER * DT_RANK / 4);

    // 1) merged x/z GEMM over full interleaved W_in (N=4096): even n -> x, odd -> z
    gemm_bt256<2><<<dim3(2 * D_INNER / 128, BL / 256), dim3(512), 98304, stream>>>(
        hxhi, hxlo, winhi, winlo, xbuf, zbuf, D_MODEL, D_MODEL, D_MODEL, D_INNER);

    // 2) depthwise causal conv + bias + SiLU -> xc hi/lo (overwrites hx/win)
    short* xchi = (short*)xcreg;
    short* xclo = xchi + (size_t)BL * D_INNER;
    conv_silu_k<<<dim3(BL * D_INNER / 256), thr, 0, stream>>>(xbuf, conv_w, conv_b, xchi, xclo);

    // 3) x_dbl = xc @ x_proj_w^T (MFMA bf16x3, N=96) + dt bf16 split emit
    gemm96<<<dim3(BL / 32), thr, 0, stream>>>(xchi, xclo, xpwhi, xpwlo, dtbc, dthi, dtlo);

    // 4) delta = softplus(dt @ dt_w^T + dt_b) -> xbuf  (128^2 kernel, K=64)
    gemm_bf16x3<1><<<dim3(D_INNER / 128, BL / 128), thr, 0, stream>>>(
        dthi, dtlo, dtwhi, dtwlo, xbuf, DT_RANK, DT_RANK, DT_RANK, D_INNER, dt_b);

    // 5-7) chunked selective scan; scan3 writes y hi/lo in-place over xchi/xclo
    scan1<<<dim3(D_INNER / 256, BATCH, NCH), thr, 0, stream>>>(
        xbuf, xchi, xclo, dtbc, A_log, sumd, Send);
    scan2<<<dim3(BATCH * 16 * D_INNER / 256), thr, 0, stream>>>(sumd, Send, A_log);
    scan3<<<dim3(D_INNER / 256, BATCH, NCH), thr, 0, stream>>>(
        xbuf, xchi, xclo, zbuf, dtbc, A_log, Send, Dp);

    // 8) split-convert W_out into zbuf (z is dead after scan3)
    short* wohi = (short*)zbuf;
    short* wolo = wohi + (size_t)D_MODEL * D_INNER;
    cvt_split<<<dim3(D_MODEL * D_INNER / 1024), thr, 0, stream>>>(W_out, wohi, wolo, D_MODEL * D_INNER / 4);

    // 9) out = y @ W_out^T  (y hi/lo live in xchi/xclo)
    gemm_bt256<0><<<dim3(D_MODEL / 128, BL / 256), dim3(512), 98304, stream>>>(
        xchi, xclo, wohi, wolo, out, nullptr, D_INNER, D_INNER, D_INNER, D_MODEL);
}

// Round 9
// 658.507 us; speedup vs baseline: 1.0997x; 1.0997x over previous
//
#include <hip/hip_runtime.h>
#include <hip/hip_bf16.h>

#define D_MODEL 1024
#define D_INNER 2048
#define D_STATE 16
#define DT_RANK 64
#define BATCH 2
#define SEQLEN 4096
#define BL (BATCH * SEQLEN)           // 8192 rows (b,l)
#define NPROJ (DT_RANK + 2 * D_STATE) // 96
#define CH 64                         // scan chunk length
#define NCH (SEQLEN / CH)             // 64 chunks

typedef __attribute__((ext_vector_type(8))) _Float16 f16x8;
typedef __attribute__((ext_vector_type(4))) float f32x4;
struct S4 { short x, y, z, w; };

__device__ __forceinline__ float sigmoidf_(float v) {
    return 1.0f / (1.0f + __expf(-v));
}
__device__ __forceinline__ short f2h(float f) {
    _Float16 h = (_Float16)f;            // v_cvt_f16_f32 (rne)
    return __builtin_bit_cast(short, h);
}
__device__ __forceinline__ float h2f(short s) {
    return (float)__builtin_bit_cast(_Float16, s);
}

#define GLOAD(gptr, dptr)                                              \
    __builtin_amdgcn_global_load_lds(                                  \
        (const __attribute__((address_space(1))) void*)(gptr),         \
        (__attribute__((address_space(3))) void*)(dptr), 16, 0, 0)

// ---------------------------------------------------------------------------
// fp32 -> fp16 single (weights; values well inside fp16 normal range)
// ---------------------------------------------------------------------------
__global__ __launch_bounds__(256)
void cvt_h(const float* __restrict__ in, short* __restrict__ out, int n4) {
    const int i = blockIdx.x * 256 + threadIdx.x;
    if (i >= n4) return;
    const float4 v = reinterpret_cast<const float4*>(in)[i];
    S4 o;
    o.x = f2h(v.x); o.y = f2h(v.y); o.z = f2h(v.z); o.w = f2h(v.w);
    *reinterpret_cast<S4*>(out + (size_t)i * 4) = o;
}

// ---------------------------------------------------------------------------
// fp32 -> fp16 hi + fp16 lo (activations; lo = rne(x - hi), err ~2^-22)
// ---------------------------------------------------------------------------
__global__ __launch_bounds__(256)
void cvt_split_h(const float* __restrict__ in, short* __restrict__ hi,
                 short* __restrict__ lo, int n4) {
    const int i = blockIdx.x * 256 + threadIdx.x;
    if (i >= n4) return;
    const float4 v = reinterpret_cast<const float4*>(in)[i];
    const float f[4] = {v.x, v.y, v.z, v.w};
    S4 h, l;
    short hb[4], lb[4];
#pragma unroll
    for (int j = 0; j < 4; ++j) {
        hb[j] = f2h(f[j]);
        lb[j] = f2h(f[j] - h2f(hb[j]));
    }
    h.x = hb[0]; h.y = hb[1]; h.z = hb[2]; h.w = hb[3];
    l.x = lb[0]; l.y = lb[1]; l.z = lb[2]; l.w = lb[3];
    *reinterpret_cast<S4*>(hi + (size_t)i * 4) = h;
    *reinterpret_cast<S4*>(lo + (size_t)i * 4) = l;
}

// ---------------------------------------------------------------------------
// fp16x2 MFMA NT GEMM: C = (Ahi+Alo)[M,K] * fp16(B)[N,K]^T.  256x128 tile,
// 8 waves, BK=32, 3-stage LDS pipeline (120 KB), 2-deep prefetch with counted
// vmcnt (5 loads/wave/K-step -> steady vmcnt(10), tail 5, last 0).
// T1 XCD swizzle; T2 XOR swizzle via pre-swizzled global source (verified,
// conflicts = 0). Per wave per K-step: 12 ds_read_b128, 32 MFMA.
// EPI 0: fp32 C0. EPI 1: fp16 C0 = softplus(v + bias[n]).
// EPI 2: even n -> fp32 C0[row*ldc + n/2], odd n -> fp16 C1[row*ldc + n/2].
// Requires M%256==0, N%128==0, K%32==0, K>=64, grid%8==0.
// ---------------------------------------------------------------------------
template <int EPI>
__global__ __launch_bounds__(512)
void gemm_f16x2(const short* __restrict__ Ahi, const short* __restrict__ Alo,
                const short* __restrict__ B, void* C0v, void* C1v,
                int K, int lda, int ldb, int ldc,
                const float* __restrict__ bias) {
    extern __shared__ short smem[];  // 3 x (Ahi 8192 + Alo 8192 + B 4096) shorts
    const int t = threadIdx.x;
    const int w = t >> 6, l = t & 63;

    // T1: XCD swizzle (callers guarantee nwg % 8 == 0)
    const int nwg = gridDim.x * gridDim.y;
    int bid = blockIdx.y * gridDim.x + blockIdx.x;
    bid = (bid & 7) * (nwg >> 3) + (bid >> 3);
    const int m0 = (bid / gridDim.x) * 256, n0 = (bid % gridDim.x) * 128;
    const int wr = w >> 1, wc = w & 1;     // wave quadrant 4x2

    const int r4 = l >> 2;                               // row within 16-seg
    const int kc_src = ((l & 3) ^ ((l >> 3) & 3)) << 3;  // T2 source chunk
    const int frow = l & 15;
    const int kb = (((l >> 4) ^ ((frow >> 1) & 3)) << 3);  // T2 read chunk

    f32x4 acc[4][4] = {};

    // 5 loads per wave per K-step: Ahi segs {2w,2w+1}, Alo segs {2w,2w+1}, B seg w
    auto STAGE = [&](int buf, int k0) {
        short* bb = smem + buf * 20480;
        const int s0 = 2 * w, s1 = 2 * w + 1;
        GLOAD(Ahi + (size_t)(m0 + s0 * 16 + r4) * lda + k0 + kc_src, bb + s0 * 512);
        GLOAD(Ahi + (size_t)(m0 + s1 * 16 + r4) * lda + k0 + kc_src, bb + s1 * 512);
        GLOAD(Alo + (size_t)(m0 + s0 * 16 + r4) * lda + k0 + kc_src, bb + 8192 + s0 * 512);
        GLOAD(Alo + (size_t)(m0 + s1 * 16 + r4) * lda + k0 + kc_src, bb + 8192 + s1 * 512);
        GLOAD(B + (size_t)(n0 + w * 16 + r4) * ldb + k0 + kc_src, bb + 16384 + w * 512);
    };

    auto COMPUTE = [&](int buf) {
        const short* bb = smem + buf * 20480;
        f16x8 ah[4], al[4], bv[4];
#pragma unroll
        for (int f = 0; f < 4; ++f) {
            ah[f] = *reinterpret_cast<const f16x8*>(&bb[(wr * 64 + f * 16 + frow) * 32 + kb]);
            al[f] = *reinterpret_cast<const f16x8*>(&bb[8192 + (wr * 64 + f * 16 + frow) * 32 + kb]);
            bv[f] = *reinterpret_cast<const f16x8*>(&bb[16384 + (wc * 64 + f * 16 + frow) * 32 + kb]);
        }
#pragma unroll
        for (int fi = 0; fi < 4; ++fi)
#pragma unroll
            for (int fj = 0; fj < 4; ++fj) {
                acc[fi][fj] = __builtin_amdgcn_mfma_f32_16x16x32_f16(
                    ah[fi], bv[fj], acc[fi][fj], 0, 0, 0);
                acc[fi][fj] = __builtin_amdgcn_mfma_f32_16x16x32_f16(
                    al[fi], bv[fj], acc[fi][fj], 0, 0, 0);
            }
    };

    const int NT = K >> 5;
    STAGE(0, 0);
    STAGE(1, 32);
    for (int tt = 0; tt < NT; ++tt) {
        const int cur = tt % 3;
        if (tt + 2 < NT) STAGE((tt + 2) % 3, (tt + 2) << 5);
        __builtin_amdgcn_sched_barrier(0);
        if (tt < NT - 2)
            asm volatile("s_waitcnt vmcnt(10)" ::: "memory");  // tile tt done, 2 in flight
        else if (tt == NT - 2)
            asm volatile("s_waitcnt vmcnt(5)" ::: "memory");
        else
            asm volatile("s_waitcnt vmcnt(0)" ::: "memory");
        __builtin_amdgcn_s_barrier();      // A: tile tt visible to all waves
        COMPUTE(cur);
        __builtin_amdgcn_sched_barrier(0); // keep ds_read/MFMA before barrier B
        __builtin_amdgcn_s_barrier();      // B: buf[cur] free for overwrite at tt+1
    }

    // C/D layout (m89-verified): col = lane&15, row = (lane>>4)*4 + reg
    const int crow = (l >> 4) << 2;
    const int ccol = l & 15;
#pragma unroll
    for (int fi = 0; fi < 4; ++fi)
#pragma unroll
        for (int fj = 0; fj < 4; ++fj) {
            const int n = n0 + wc * 64 + fj * 16 + ccol;
#pragma unroll
            for (int r = 0; r < 4; ++r) {
                const float v = acc[fi][fj][r];
                const size_t row = (size_t)(m0 + wr * 64 + fi * 16 + crow + r);
                if (EPI == 0) {
                    ((float*)C0v)[row * ldc + n] = v;
                } else if (EPI == 1) {
                    float s = v + bias[n];
                    s = fmaxf(s, 0.f) + log1pf(__expf(-fabsf(s)));  // stable softplus
                    ((short*)C0v)[row * ldc + n] = f2h(s);          // delta as fp16
                } else {  // EPI == 2: parity split, x fp32 / z fp16
                    if (n & 1) ((short*)C1v)[row * ldc + (n >> 1)] = f2h(v);
                    else       ((float*)C0v)[row * ldc + (n >> 1)] = v;
                }
            }
        }
}

// ---------------------------------------------------------------------------
// Tall-skinny fp16x2 MFMA GEMM for x_proj: C[BL x 96] = (Xhi+Xlo)*fp16(W)^T.
// No LDS: W is L2 resident. Emits dt cols (0..63) as fp16 hi/lo for delta GEMM.
// ---------------------------------------------------------------------------
__global__ __launch_bounds__(256)
void gemm96(const short* __restrict__ Xhi, const short* __restrict__ Xlo,
            const short* __restrict__ W, float* __restrict__ C,
            short* __restrict__ dthi, short* __restrict__ dtlo) {
    const int t = threadIdx.x;
    const int w = t >> 6, l = t & 63;
    const int m0 = blockIdx.x * 32;
    const int rfrag = (w >> 1) * 16;
    const int cbase = (w & 1) * 48;
    const int lrow = l & 15;
    const int koff0 = (l >> 4) << 3;
    f32x4 acc[3] = {};
    const size_t arow = (size_t)(m0 + rfrag + lrow) * D_INNER;
#pragma unroll 2
    for (int k0 = 0; k0 < D_INNER; k0 += 32) {
        const int ko = k0 + koff0;
        const f16x8 ah = *reinterpret_cast<const f16x8*>(Xhi + arow + ko);
        const f16x8 al = *reinterpret_cast<const f16x8*>(Xlo + arow + ko);
#pragma unroll
        for (int jj = 0; jj < 3; ++jj) {
            const size_t brow = (size_t)(cbase + jj * 16 + lrow) * D_INNER + ko;
            const f16x8 bw = *reinterpret_cast<const f16x8*>(W + brow);
            acc[jj] = __builtin_amdgcn_mfma_f32_16x16x32_f16(ah, bw, acc[jj], 0, 0, 0);
            acc[jj] = __builtin_amdgcn_mfma_f32_16x16x32_f16(al, bw, acc[jj], 0, 0, 0);
        }
    }
    const int crow = (l >> 4) << 2;
#pragma unroll
    for (int jj = 0; jj < 3; ++jj) {
        const int col = cbase + jj * 16 + lrow;
#pragma unroll
        for (int r = 0; r < 4; ++r) {
            const int m = m0 + rfrag + crow + r;
            const float v = acc[jj][r];
            C[(size_t)m * NPROJ + col] = v;
            if (col < DT_RANK) {
                const short hh = f2h(v);
                dthi[(size_t)m * DT_RANK + col] = hh;
                dtlo[(size_t)m * DT_RANK + col] = f2h(v - h2f(hh));
            }
        }
    }
}

// ---------------------------------------------------------------------------
// Depthwise causal conv (D_CONV=4) + bias + SiLU -> fp16 hi/lo split output.
// ---------------------------------------------------------------------------
__global__ __launch_bounds__(256)
void conv_silu_k(const float* __restrict__ xr, const float* __restrict__ cw,
                 const float* __restrict__ cb, short* __restrict__ xchi,
                 short* __restrict__ xclo) {
    const int idx = blockIdx.x * 256 + threadIdx.x;
    const int d = idx & (D_INNER - 1);
    const int bl = idx >> 11;
    const int l = bl & (SEQLEN - 1);
    const float4 w4 = *reinterpret_cast<const float4*>(cw + (size_t)d * 4);
    const float wj[4] = {w4.x, w4.y, w4.z, w4.w};
    float acc = cb[d];
#pragma unroll
    for (int j = 0; j < 4; ++j) {
        const int ll = l - 3 + j;
        if (ll >= 0)
            acc += xr[(size_t)(bl - 3 + j) * D_INNER + d] * wj[j];
    }
    const float v = acc * sigmoidf_(acc);
    const short hh = f2h(v);
    xchi[idx] = hh;
    xclo[idx] = f2h(v - h2f(hh));
}

// ---------------------------------------------------------------------------
// Selective scan, chunked 3-pass. x reconstructed from fp16 hi/lo (~2^-22);
// delta read as fp16 (err 2^-11 rel, harmless in exp path).
// ---------------------------------------------------------------------------
__global__ __launch_bounds__(256)
void scan1(const short* __restrict__ delta, const short* __restrict__ xchi,
           const short* __restrict__ xclo, const float* __restrict__ dtbc,
           const float* __restrict__ A_log, float* __restrict__ sum_delta,
           float* __restrict__ S_end) {
    const int d = blockIdx.x * 256 + threadIdx.x;
    const int b = blockIdx.y;
    const int c = blockIdx.z;
    __shared__ float bc[CH][32];
    for (int i = threadIdx.x; i < CH * 32; i += 256) {
        const int row = i >> 5, col = i & 31;
        bc[row][col] = dtbc[(size_t)(b * SEQLEN + c * CH + row) * NPROJ + DT_RANK + col];
    }
    __syncthreads();
    float A[16];
#pragma unroll
    for (int n = 0; n < 16; ++n) A[n] = -__expf(A_log[(size_t)d * 16 + n]);
    float s[16] = {0.f};
    float sd = 0.f;
    const size_t base = ((size_t)b * SEQLEN + (size_t)c * CH) * D_INNER + d;
    for (int li = 0; li < CH; ++li) {
        const size_t o = base + (size_t)li * D_INNER;
        const float dl = h2f(delta[o]);
        const float xv = h2f(xchi[o]) + h2f(xclo[o]);
        sd += dl;
        const float dx = dl * xv;
#pragma unroll
        for (int n = 0; n < 16; ++n) {
            const float a = __expf(dl * A[n]);
            s[n] = fmaf(s[n], a, dx * bc[li][n]);
        }
    }
    sum_delta[((size_t)c * BATCH + b) * D_INNER + d] = sd;
#pragma unroll
    for (int n = 0; n < 16; ++n)
        S_end[(((size_t)c * BATCH + b) * 16 + n) * D_INNER + d] = s[n];
}

// Thread per (b,d,n); in-place: S holds end-states on entry, init-states on exit.
__global__ __launch_bounds__(256)
void scan2(const float* __restrict__ sum_delta, float* __restrict__ S,
           const float* __restrict__ A_log) {
    const int idx = blockIdx.x * 256 + threadIdx.x;   // [0, BATCH*16*D_INNER)
    const int d = idx & (D_INNER - 1);
    const int n = (idx >> 11) & 15;
    const int b = idx >> 15;
    const float A = -__expf(A_log[(size_t)d * 16 + n]);
    float carry = 0.f;
    for (int c = 0; c < NCH; ++c) {
        const float sd = sum_delta[((size_t)c * BATCH + b) * D_INNER + d];
        const size_t o = (((size_t)c * BATCH + b) * 16 + n) * D_INNER + d;
        const float se = S[o];
        S[o] = carry;
        carry = fmaf(carry, __expf(sd * A), se);
    }
}

// scan3: writes gated y as fp16 hi/lo IN-PLACE over xchi/xclo.
__global__ __launch_bounds__(256)
void scan3(const short* __restrict__ delta, short* __restrict__ xchi,
           short* __restrict__ xclo, const short* __restrict__ z,
           const float* __restrict__ dtbc, const float* __restrict__ A_log,
           const float* __restrict__ S_init, const float* __restrict__ Dp) {
    const int d = blockIdx.x * 256 + threadIdx.x;
    const int b = blockIdx.y;
    const int c = blockIdx.z;
    __shared__ float bc[CH][32];
    for (int i = threadIdx.x; i < CH * 32; i += 256) {
        const int row = i >> 5, col = i & 31;
        bc[row][col] = dtbc[(size_t)(b * SEQLEN + c * CH + row) * NPROJ + DT_RANK + col];
    }
    __syncthreads();
    float A[16];
#pragma unroll
    for (int n = 0; n < 16; ++n) A[n] = -__expf(A_log[(size_t)d * 16 + n]);
    float s[16];
#pragma unroll
    for (int n = 0; n < 16; ++n)
        s[n] = S_init[(((size_t)c * BATCH + b) * 16 + n) * D_INNER + d];
    const float Dv = Dp[d];
    const size_t base = ((size_t)b * SEQLEN + (size_t)c * CH) * D_INNER + d;
    for (int li = 0; li < CH; ++li) {
        const size_t o = base + (size_t)li * D_INNER;
        const float dl = h2f(delta[o]);
        const float xv = h2f(xchi[o]) + h2f(xclo[o]);
        const float dx = dl * xv;
        float y = 0.f;
#pragma unroll
        for (int n = 0; n < 16; ++n) {
            const float a = __expf(dl * A[n]);
            s[n] = fmaf(s[n], a, dx * bc[li][n]);
            y = fmaf(s[n], bc[li][16 + n], y);
        }
        const float zv = h2f(z[o]);
        const float yv = (y + Dv * xv) * (zv * sigmoidf_(zv));
        const short hh = f2h(yv);
        xchi[o] = hh;
        xclo[o] = f2h(yv - h2f(hh));
    }
}

// ---------------------------------------------------------------------------
extern "C" void kernel_launch(void* const* d_in, const int* in_sizes, int n_in,
                              void* d_out, int out_size, void* d_ws, size_t ws_size,
                              hipStream_t stream) {
    const float* hidden   = (const float*)d_in[0];
    const float* W_in     = (const float*)d_in[1];
    const float* conv_w   = (const float*)d_in[2];
    const float* conv_b   = (const float*)d_in[3];
    const float* x_proj_w = (const float*)d_in[4];
    const float* dt_w     = (const float*)d_in[5];
    const float* dt_b     = (const float*)d_in[6];
    const float* A_log    = (const float*)d_in[7];
    const float* Dp       = (const float*)d_in[8];
    const float* W_out    = (const float*)d_in[9];
    float* out = (float*)d_out;

    // Workspace (floats), peak ~226 MB:
    float* ws    = (float*)d_ws;
    float* xbuf  = ws;                                    // BL*D_INNER fp32 (x); then fp16 delta
    float* zbuf  = xbuf + (size_t)BL * D_INNER;           // fp16 z; later W_out fp16
    float* xcreg = zbuf + (size_t)BL * D_INNER;           // splits; xc hi/lo; y hi/lo
    float* dtbc  = xcreg + (size_t)BL * D_INNER;          // BL*NPROJ fp32
    float* sumd  = dtbc + (size_t)BL * NPROJ;             // NCH*BATCH*D_INNER
    float* Send  = sumd + (size_t)NCH * BATCH * D_INNER;  // NCH*BATCH*16*D_INNER

    short* xpwh = (short*)(Send + (size_t)NCH * BATCH * 16 * D_INNER);
    short* dtwh = xpwh + (size_t)NPROJ * D_INNER;         // dt_w fp16
    short* dthi = dtwh + (size_t)D_INNER * DT_RANK;       // dt fp16 hi/lo
    short* dtlo = dthi + (size_t)BL * DT_RANK;

    short* hxhi = (short*)xcreg;                           // BL*D_MODEL fp16 hi/lo
    short* hxlo = hxhi + (size_t)BL * D_MODEL;
    short* winh = hxlo + (size_t)BL * D_MODEL;             // 2*D_INNER*D_MODEL fp16

    const dim3 thr(256);

    // 0) conversions: hidden -> hi/lo fp16; weights -> single fp16
    cvt_split_h<<<dim3(BL * D_MODEL / 1024), thr, 0, stream>>>(hidden, hxhi, hxlo, BL * D_MODEL / 4);
    cvt_h<<<dim3(2 * D_INNER * D_MODEL / 1024), thr, 0, stream>>>(W_in, winh, 2 * D_INNER * D_MODEL / 4);
    cvt_h<<<dim3(NPROJ * D_INNER / 1024), thr, 0, stream>>>(x_proj_w, xpwh, NPROJ * D_INNER / 4);
    cvt_h<<<dim3(D_INNER * DT_RANK / 1024), thr, 0, stream>>>(dt_w, dtwh, D_INNER * DT_RANK / 4);

    // 1) merged x/z GEMM over interleaved W_in (N=4096): even n -> x fp32, odd -> z fp16
    short* zh = (short*)zbuf;
    gemm_f16x2<2><<<dim3(2 * D_INNER / 128, BL / 256), dim3(512), 122880, stream>>>(
        hxhi, hxlo, winh, xbuf, zh, D_MODEL, D_MODEL, D_MODEL, D_INNER, nullptr);

    // 2) depthwise causal conv + bias + SiLU -> xc hi/lo fp16 (overwrites hx/win)
    short* xchi = (short*)xcreg;
    short* xclo = xchi + (size_t)BL * D_INNER;
    conv_silu_k<<<dim3(BL * D_INNER / 256), thr, 0, stream>>>(xbuf, conv_w, conv_b, xchi, xclo);

    // 3) x_dbl = xc @ x_proj_w^T (fp16x2, N=96) + dt fp16 hi/lo emit
    gemm96<<<dim3(BL / 32), thr, 0, stream>>>(xchi, xclo, xpwh, dtbc, dthi, dtlo);

    // 4) delta = softplus(dt @ dt_w^T + dt_b) -> fp16 into xbuf (x is dead)
    short* deltah = (short*)xbuf;
    gemm_f16x2<1><<<dim3(D_INNER / 128, BL / 256), dim3(512), 122880, stream>>>(
        dthi, dtlo, dtwh, deltah, nullptr, DT_RANK, DT_RANK, DT_RANK, D_INNER, dt_b);

    // 5-7) chunked selective scan; scan3 writes y hi/lo in-place over xchi/xclo
    scan1<<<dim3(D_INNER / 256, BATCH, NCH), thr, 0, stream>>>(
        deltah, xchi, xclo, dtbc, A_log, sumd, Send);
    scan2<<<dim3(BATCH * 16 * D_INNER / 256), thr, 0, stream>>>(sumd, Send, A_log);
    scan3<<<dim3(D_INNER / 256, BATCH, NCH), thr, 0, stream>>>(
        deltah, xchi, xclo, zh, dtbc, A_log, Send, Dp);

    // 8) W_out -> fp16 into zbuf (z dead after scan3)
    short* woh = (short*)zbuf;
    cvt_h<<<dim3(D_MODEL * D_INNER / 1024), thr, 0, stream>>>(W_out, woh, D_MODEL * D_INNER / 4);

    // 9) out = y @ W_out^T  (y hi/lo live in xchi/xclo)
    gemm_f16x2<0><<<dim3(D_MODEL / 128, BL / 256), dim3(512), 122880, stream>>>(
        xchi, xclo, woh, out, nullptr, D_INNER, D_INNER, D_INNER, D_MODEL, nullptr);
}